// Round 1
// baseline (1439.486 us; speedup 1.0000x reference)
//
#include <hip/hip_runtime.h>
#include <math.h>

// ---------------------------------------------------------------------------
// MultiSensor TSCMamba forward, fp32 throughout.
// Stage map:
//   k_patch_conv : 16x16/s16 patch conv for x/y/z  -> P[3][32][32][196]   (the big one)
//   k_proj       : P @ proj_w.T + pb, gelu, swapaxes -> R[3][32][256][32]; also feats[:,0:768] (means)
//   k_cross      : 3 pair cross-convs (k=3,pad1) + BN + gelu, ONLY channel means -> feats[:,768:1536] (atomic)
//   k_fuse       : feats @ fu_w.T + BN + gelu + LayerNorm -> xf[32][256]
//   k_m1 (x2)    : mamba with L=1 (scan degenerates closed-form) -> XF1;  x1 = 2*XF1
//   k_m2 (x2)    : mamba with D=1, L=256 (real scan), fwd+flipped batched as 64 seqs
//   k_final      : x3 = M2b[2b]+M2b[2b+1]+2*XF1 ; two small linears -> out[32][18]
// ---------------------------------------------------------------------------

__device__ __forceinline__ float gelu_f(float x) {
    return 0.5f * x * (1.0f + erff(x * 0.70710678118654752f));
}
__device__ __forceinline__ float silu_f(float x) {
    return x / (1.0f + expf(-x));
}
__device__ __forceinline__ float softplus_f(float x) {
    return (x > 20.0f) ? x : log1pf(expf(x));
}

// ---------------------------------------------------------------------------
// Kernel 1: patch conv.  grid = 3*32*14 blocks, 256 threads.
// Block owns (s, b, ph): outputs 14 pw x 32 co, K = 32ci*16kh*16kw.
// Thread tile: 7 pw x 16 co, K-split 64-way over (kh, kw-quad).
// ---------------------------------------------------------------------------
__global__ __launch_bounds__(256, 2)
void k_patch_conv(const float* __restrict__ X0, const float* __restrict__ X1, const float* __restrict__ X2,
                  const float* __restrict__ W0, const float* __restrict__ W1, const float* __restrict__ W2,
                  const float* __restrict__ B0, const float* __restrict__ B1, const float* __restrict__ B2,
                  float* __restrict__ P) {
    int bid = blockIdx.x;
    int s = bid / 448; int rem = bid % 448; int b = rem / 14; int ph = rem % 14;
    const float* X  = (s == 0) ? X0 : ((s == 1) ? X1 : X2);
    const float* W  = (s == 0) ? W0 : ((s == 1) ? W1 : W2);
    const float* Bb = (s == 0) ? B0 : ((s == 1) ? B1 : B2);

    __shared__ float4 xs4[16 * 57];   // 16 rows x 224 floats (57 f4/row: +1 f4 pad vs 56 to spread banks)
    __shared__ float4 ws4[32 * 64];   // [co][kh*4+kwq]
    __shared__ float  red[16 * 112];  // cross-wave reduction

    int tid = threadIdx.x;
    int ij = tid & 3;
    int i  = ij & 1;        // pw half  (pw = i*7 + p)
    int j  = ij >> 1;       // co half  (co = j*16 + c)
    int k  = tid >> 2;      // 0..63 over (kh, kw-quad)
    int kh = k >> 2;
    int kwq = k & 3;

    float acc[7][16];
#pragma unroll
    for (int p = 0; p < 7; ++p) {
#pragma unroll
        for (int c = 0; c < 16; ++c) acc[p][c] = 0.f;
    }

    for (int ci = 0; ci < 32; ++ci) {
        __syncthreads();
        // x slice: rows 16*ph..16*ph+15, all 224 cols of channel ci -> contiguous 3584 floats
        const float4* xg = (const float4*)(X + ((size_t)(b * 32 + ci)) * 50176 + (size_t)ph * 3584);
        for (int t = tid; t < 896; t += 256) {
            int r = t / 56, c4 = t % 56;
            xs4[r * 57 + c4] = xg[t];
        }
        // weight slice: w[co][ci][kh][kw] for all co
        const float4* wg = (const float4*)W;
        for (int t = tid; t < 2048; t += 256) {
            int co = t >> 6, q = t & 63;
            ws4[t] = wg[(size_t)(co * 32 + ci) * 64 + q];
        }
        __syncthreads();

        float4 xv[7];
        const float4* xr_ = &xs4[kh * 57 + i * 28 + kwq];
#pragma unroll
        for (int p = 0; p < 7; ++p) xv[p] = xr_[p * 4];
#pragma unroll
        for (int c = 0; c < 16; ++c) {
            float4 wv = ws4[(j * 16 + c) * 64 + k];
#pragma unroll
            for (int p = 0; p < 7; ++p) {
                acc[p][c] += xv[p].x * wv.x + xv[p].y * wv.y + xv[p].z * wv.z + xv[p].w * wv.w;
            }
        }
    }

    // reduce over k within wave (16 k-values per wave live on lane bits 2..5)
#pragma unroll
    for (int p = 0; p < 7; ++p) {
#pragma unroll
        for (int c = 0; c < 16; ++c) {
            float v = acc[p][c];
            v += __shfl_xor(v, 4);
            v += __shfl_xor(v, 8);
            v += __shfl_xor(v, 16);
            v += __shfl_xor(v, 32);
            acc[p][c] = v;
        }
    }
    int wave = tid >> 6, lane = tid & 63;
    if (lane < 4) {  // lane == its ij
#pragma unroll
        for (int p = 0; p < 7; ++p) {
#pragma unroll
            for (int c = 0; c < 16; ++c) {
                red[(wave * 4 + lane) * 112 + p * 16 + c] = acc[p][c];
            }
        }
    }
    __syncthreads();
    for (int t = tid; t < 448; t += 256) {
        int ij2 = t / 112, v = t % 112;
        int p = v / 16, c = v % 16;
        float sum = red[(0 * 4 + ij2) * 112 + v] + red[(1 * 4 + ij2) * 112 + v] +
                    red[(2 * 4 + ij2) * 112 + v] + red[(3 * 4 + ij2) * 112 + v];
        int pw = (ij2 & 1) * 7 + p;
        int co = (ij2 >> 1) * 16 + c;
        P[(((size_t)s * 32 + b) * 32 + co) * 196 + ph * 14 + pw] = sum + Bb[co];
    }
}

// ---------------------------------------------------------------------------
// Kernel 2: projection (196 -> 256) + bias + gelu + swapaxes; fused xr/yr/zr means.
// grid = 3*32*2 = 192 blocks, 128 threads (thread = one l of its half).
// ---------------------------------------------------------------------------
__global__ __launch_bounds__(128)
void k_proj(const float* __restrict__ P,
            const float* __restrict__ PW0, const float* __restrict__ PW1, const float* __restrict__ PW2,
            const float* __restrict__ PB0, const float* __restrict__ PB1, const float* __restrict__ PB2,
            float* __restrict__ R, float* __restrict__ feats) {
    int bid = blockIdx.x;
    int s = bid / 64; int r2 = bid % 64; int b = r2 >> 1; int half = r2 & 1;
    const float* PW = (s == 0) ? PW0 : ((s == 1) ? PW1 : PW2);
    const float* PB = (s == 0) ? PB0 : ((s == 1) ? PB1 : PB2);

    __shared__ float4 ps4[32 * 49];  // P[b]: 32 co x 196 n
    const float4* src = (const float4*)(P + ((size_t)s * 32 + b) * 6272);
    for (int t = threadIdx.x; t < 1568; t += 128) ps4[t] = src[t];
    __syncthreads();

    int l = half * 128 + threadIdx.x;
    float acc[32];
#pragma unroll
    for (int c = 0; c < 32; ++c) acc[c] = 0.f;

    const float4* pwl = (const float4*)(PW + (size_t)l * 196);
    for (int n4 = 0; n4 < 49; ++n4) {
        float4 pv = pwl[n4];
#pragma unroll
        for (int c = 0; c < 32; ++c) {
            float4 xv = ps4[c * 49 + n4];
            acc[c] += pv.x * xv.x + pv.y * xv.y + pv.z * xv.z + pv.w * xv.w;
        }
    }
    float pbl = PB[l];
    float m = 0.f;
    float* Rrow = R + (((size_t)s * 32 + b) * 256 + l) * 32;
#pragma unroll
    for (int c = 0; c < 32; ++c) {
        float v = gelu_f(acc[c] + pbl);
        Rrow[c] = v;
        m += v;
    }
    feats[b * 1536 + s * 256 + l] = m * 0.03125f;
}

// ---------------------------------------------------------------------------
// Kernel 3: cross conv (k=3, pad 1) + BN + gelu, channel means only.
// grid = 32 b x 8 c-slices = 256 blocks, 256 threads (thread = out channel o).
// All 3 pairs computed per weight load:  i<256: (x,x,y); i>=256: (y,z,z).
// ---------------------------------------------------------------------------
__global__ __launch_bounds__(256)
void k_cross(const float* __restrict__ R, const float* __restrict__ CCW,
             const float* __restrict__ CCB, const float* __restrict__ CCG,
             const float* __restrict__ CCBETA, const float* __restrict__ CCRM,
             const float* __restrict__ CCRV, float* __restrict__ feats) {
    int b = blockIdx.x >> 3, cs = blockIdx.x & 7;
    int c0 = cs * 4;
    __shared__ float ls[3 * 256 * 8];  // [tensor][row i][col 0..5 used] (cols = c0-1 .. c0+4, zero padded)
    for (int t = threadIdx.x; t < 4608; t += 256) {
        int ten = t / 1536; int r2 = t % 1536; int r = r2 / 6; int cc = r2 % 6;
        int cg = c0 - 1 + cc;
        float v = 0.f;
        if (cg >= 0 && cg < 32) v = R[(((size_t)ten * 32 + b) * 256 + r) * 32 + cg];
        ls[(ten * 256 + r) * 8 + cc] = v;
    }
    __syncthreads();

    int o = threadIdx.x;
    float a1[4] = {0, 0, 0, 0}, a2[4] = {0, 0, 0, 0}, a3[4] = {0, 0, 0, 0};
    const float* wrow = CCW + (size_t)o * 1536;

    for (int ii = 0; ii < 256; ++ii) {
        float w0 = wrow[ii * 3], w1 = wrow[ii * 3 + 1], w2 = wrow[ii * 3 + 2];
        const float* U = &ls[(0 * 256 + ii) * 8];  // x
        const float* V = &ls[(1 * 256 + ii) * 8];  // y
#pragma unroll
        for (int c = 0; c < 4; ++c) {
            float su_ = w0 * U[c] + w1 * U[c + 1] + w2 * U[c + 2];
            float sv_ = w0 * V[c] + w1 * V[c + 1] + w2 * V[c + 2];
            a1[c] += su_; a2[c] += su_; a3[c] += sv_;
        }
    }
    for (int ii = 0; ii < 256; ++ii) {
        float w0 = wrow[768 + ii * 3], w1 = wrow[768 + ii * 3 + 1], w2 = wrow[768 + ii * 3 + 2];
        const float* U = &ls[(1 * 256 + ii) * 8];  // y
        const float* V = &ls[(2 * 256 + ii) * 8];  // z
#pragma unroll
        for (int c = 0; c < 4; ++c) {
            float su_ = w0 * U[c] + w1 * U[c + 1] + w2 * U[c + 2];
            float sv_ = w0 * V[c] + w1 * V[c + 1] + w2 * V[c + 2];
            a1[c] += su_; a2[c] += sv_; a3[c] += sv_;
        }
    }

    float inv = CCG[o] / sqrtf(CCRV[o] + 1e-5f);
    float sh = CCBETA[o] - CCRM[o] * inv;
    float bias = CCB[o];
    float s1 = 0.f, s2 = 0.f, s3 = 0.f;
#pragma unroll
    for (int c = 0; c < 4; ++c) {
        s1 += gelu_f((a1[c] + bias) * inv + sh);
        s2 += gelu_f((a2[c] + bias) * inv + sh);
        s3 += gelu_f((a3[c] + bias) * inv + sh);
    }
    float* fb = feats + b * 1536 + 768;
    atomicAdd(&fb[o],       s1 * 0.03125f);
    atomicAdd(&fb[256 + o], s2 * 0.03125f);
    atomicAdd(&fb[512 + o], s3 * 0.03125f);
}

// ---------------------------------------------------------------------------
// Kernel 4: fuse linear + BN + gelu + LayerNorm.  grid = 32, 256 threads.
// ---------------------------------------------------------------------------
__global__ __launch_bounds__(256)
void k_fuse(const float* __restrict__ feats, const float* __restrict__ FUW, const float* __restrict__ FUB,
            const float* __restrict__ FUG, const float* __restrict__ FUBETA, const float* __restrict__ FURM,
            const float* __restrict__ FURV, const float* __restrict__ LNG, const float* __restrict__ LNB,
            float* __restrict__ xf) {
    int b = blockIdx.x;
    __shared__ float4 sf4[384];
    const float4* src = (const float4*)(feats + (size_t)b * 1536);
    for (int t = threadIdx.x; t < 384; t += 256) sf4[t] = src[t];
    __syncthreads();

    int o = threadIdx.x;
    const float4* wr = (const float4*)(FUW + (size_t)o * 1536);
    float acc = 0.f;
    for (int q = 0; q < 384; ++q) {
        float4 wv = wr[q], xv = sf4[q];
        acc += wv.x * xv.x + wv.y * xv.y + wv.z * xv.z + wv.w * xv.w;
    }
    float inv = FUG[o] / sqrtf(FURV[o] + 1e-5f);
    float f = (acc + FUB[o]) * inv + (FUBETA[o] - FURM[o] * inv);
    f = gelu_f(f);

    float s1 = f, s2 = f * f;
#pragma unroll
    for (int off = 32; off >= 1; off >>= 1) {
        s1 += __shfl_xor(s1, off);
        s2 += __shfl_xor(s2, off);
    }
    __shared__ float wred[8];
    int wave = threadIdx.x >> 6, lane = threadIdx.x & 63;
    if (lane == 0) { wred[wave * 2] = s1; wred[wave * 2 + 1] = s2; }
    __syncthreads();
    float mu  = (wred[0] + wred[2] + wred[4] + wred[6]) * (1.f / 256.f);
    float ex2 = (wred[1] + wred[3] + wred[5] + wred[7]) * (1.f / 256.f);
    float var = ex2 - mu * mu;
    xf[b * 256 + o] = (f - mu) / sqrtf(var + 1e-5f) * LNG[o] + LNB[o];
}

// ---------------------------------------------------------------------------
// Kernel 5: m1 mamba layer, L = 1 (closed form; Alog unused since h0 = 0).
// grid = 32 (b), 256 threads.
// ---------------------------------------------------------------------------
__global__ __launch_bounds__(256)
void k_m1(const float* __restrict__ Uin, float* __restrict__ Uout,
          const float* __restrict__ WIN, const float* __restrict__ CW, const float* __restrict__ CB,
          const float* __restrict__ WX, const float* __restrict__ WDT, const float* __restrict__ BDT,
          const float* __restrict__ DP, const float* __restrict__ WOUT, int layer) {
    const float* Win  = WIN  + (size_t)layer * 1024 * 256;
    const float* cw   = CW   + layer * 2048;
    const float* cb   = CB   + layer * 512;
    const float* Wx   = WX   + layer * 48 * 512;
    const float* Wdt  = WDT  + layer * 512 * 16;
    const float* bdt  = BDT  + layer * 512;
    const float* Dp   = DP   + layer * 512;
    const float* Wout = WOUT + layer * 256 * 512;

    int b = blockIdx.x, tid = threadIdx.x;
    __shared__ float su[256];
    __shared__ float sz[1024];
    __shared__ float sx[512];
    __shared__ float sdbc[48];
    __shared__ float sy[512];

    su[tid] = Uin[b * 256 + tid];
    __syncthreads();

    const float4* su4 = (const float4*)su;
#pragma unroll
    for (int q = 0; q < 4; ++q) {
        int e = tid + q * 256;
        const float4* wr = (const float4*)(Win + (size_t)e * 256);
        float acc = 0.f;
        for (int t = 0; t < 64; ++t) {
            float4 wv = wr[t], xv = su4[t];
            acc += wv.x * xv.x + wv.y * xv.y + wv.z * xv.z + wv.w * xv.w;
        }
        sz[e] = acc;
    }
    __syncthreads();
#pragma unroll
    for (int q = 0; q < 2; ++q) {
        int d = tid + q * 256;
        sx[d] = silu_f(cb[d] + sz[d] * cw[d * 4 + 3]);  // K=4, L=1 -> only tap k=3
    }
    __syncthreads();
    if (tid < 48) {
        const float4* wr = (const float4*)(Wx + (size_t)tid * 512);
        const float4* sx4 = (const float4*)sx;
        float acc = 0.f;
        for (int t = 0; t < 128; ++t) {
            float4 wv = wr[t], xv = sx4[t];
            acc += wv.x * xv.x + wv.y * xv.y + wv.z * xv.z + wv.w * xv.w;
        }
        sdbc[tid] = acc;
    }
    __syncthreads();
    float bc = 0.f;
#pragma unroll
    for (int n = 0; n < 16; ++n) bc += sdbc[16 + n] * sdbc[32 + n];
#pragma unroll
    for (int q = 0; q < 2; ++q) {
        int d = tid + q * 256;
        float dtin = 0.f;
#pragma unroll
        for (int r = 0; r < 16; ++r) dtin += sdbc[r] * Wdt[d * 16 + r];
        float dtv = softplus_f(dtin + bdt[d]);
        float xcv = sx[d];
        float y = dtv * xcv * bc + Dp[d] * xcv;
        y *= silu_f(sz[512 + d]);
        sy[d] = y;
    }
    __syncthreads();
    {
        const float4* wr = (const float4*)(Wout + (size_t)tid * 512);
        const float4* sy4 = (const float4*)sy;
        float acc = 0.f;
        for (int t = 0; t < 128; ++t) {
            float4 wv = wr[t], xv = sy4[t];
            acc += wv.x * xv.x + wv.y * xv.y + wv.z * xv.z + wv.w * xv.w;
        }
        Uout[b * 256 + tid] = acc + su[tid];  // residual
    }
}

// ---------------------------------------------------------------------------
// Kernel 6: m2 mamba layer, D=1 seq of L=256; 64 sequences (32 b x {fwd,flip}).
// grid = 64, 256 threads (thread = position l). 32-thread scan.
// ---------------------------------------------------------------------------
__global__ __launch_bounds__(256)
void k_m2(const float* __restrict__ SRC, float* __restrict__ DST, int first,
          const float* __restrict__ WIN, const float* __restrict__ CW, const float* __restrict__ CB,
          const float* __restrict__ WX, const float* __restrict__ WDT, const float* __restrict__ BDT,
          const float* __restrict__ ALOG, const float* __restrict__ DP, const float* __restrict__ WOUT,
          int layer) {
    const float* Win  = WIN  + layer * 4;
    const float* cw   = CW   + layer * 8;
    const float* cb   = CB   + layer * 2;
    const float* Wx   = WX   + layer * 66;
    const float* Wdt  = WDT  + layer * 2;
    const float* bdt  = BDT  + layer * 2;
    const float* Alog = ALOG + layer * 32;
    const float* Dp   = DP   + layer * 2;
    const float* Wout = WOUT + layer * 2;

    int v = blockIdx.x, b = v >> 1, dir = v & 1, l = threadIdx.x;
    __shared__ float sxc[256 * 2];
    __shared__ float sC[256 * 16];
    __shared__ float suu[256 * 32];
    __shared__ float sdt[256 * 2];
    __shared__ float sy[256 * 2];

    float u;
    if (first) u = 2.f * SRC[b * 256 + (dir ? (255 - l) : l)];  // x1 = 2*XF1, flipped for dir=1
    else       u = SRC[v * 256 + l];

    float xc0 = u * Win[0], xc1 = u * Win[1];
    float z0  = u * Win[2], z1  = u * Win[3];
    sxc[l * 2 + 0] = xc0; sxc[l * 2 + 1] = xc1;
    __syncthreads();

    float xs0, xs1;
    {
        float a0 = cb[0], a1 = cb[1];
#pragma unroll
        for (int kk = 0; kk < 4; ++kk) {
            int lk = l - 3 + kk;
            if (lk >= 0) {
                a0 += sxc[lk * 2 + 0] * cw[kk];
                a1 += sxc[lk * 2 + 1] * cw[4 + kk];
            }
        }
        xs0 = silu_f(a0); xs1 = silu_f(a1);
    }
    float dbc0 = xs0 * Wx[0] + xs1 * Wx[1];
    float dt0 = softplus_f(dbc0 * Wdt[0] + bdt[0]);
    float dt1 = softplus_f(dbc0 * Wdt[1] + bdt[1]);
    sdt[l * 2 + 0] = dt0; sdt[l * 2 + 1] = dt1;
#pragma unroll
    for (int n = 0; n < 16; ++n) {
        float Bn = xs0 * Wx[(1 + n) * 2] + xs1 * Wx[(1 + n) * 2 + 1];
        float Cn = xs0 * Wx[(17 + n) * 2] + xs1 * Wx[(17 + n) * 2 + 1];
        sC[l * 16 + n] = Cn;
        suu[l * 32 + n]      = dt0 * Bn * xs0;
        suu[l * 32 + 16 + n] = dt1 * Bn * xs1;
    }
    __syncthreads();

    if (l < 32) {
        int d = l >> 4, n = l & 15;
        float A = -expf(Alog[d * 16 + n]);
        float h = 0.f;
#pragma unroll 4
        for (int t = 0; t < 256; ++t) {
            float a = expf(sdt[t * 2 + d] * A);
            h = a * h + suu[t * 32 + l];
            float part = h * sC[t * 16 + n];
            part += __shfl_xor(part, 1);
            part += __shfl_xor(part, 2);
            part += __shfl_xor(part, 4);
            part += __shfl_xor(part, 8);
            if (n == 0) sy[t * 2 + d] = part;
        }
    }
    __syncthreads();
    {
        float y0 = sy[l * 2 + 0] + Dp[0] * xs0;
        float y1 = sy[l * 2 + 1] + Dp[1] * xs1;
        y0 *= silu_f(z0); y1 *= silu_f(z1);
        DST[v * 256 + l] = y0 * Wout[0] + y1 * Wout[1] + u;  // residual
    }
}

// ---------------------------------------------------------------------------
// Kernel 7: final combine + classifier. grid = 32, 256 threads.
// ---------------------------------------------------------------------------
__global__ __launch_bounds__(256)
void k_final(const float* __restrict__ M2b, const float* __restrict__ XF1,
             const float* __restrict__ CL1W, const float* __restrict__ CL1B,
             const float* __restrict__ CL2W, const float* __restrict__ CL2B,
             float* __restrict__ out) {
    int b = blockIdx.x, tid = threadIdx.x;
    __shared__ float sx3[256];
    __shared__ float shh[128];
    sx3[tid] = M2b[(2 * b) * 256 + tid] + M2b[(2 * b + 1) * 256 + tid] + 2.f * XF1[b * 256 + tid];
    __syncthreads();
    if (tid < 128) {
        const float4* wr = (const float4*)(CL1W + (size_t)tid * 256);
        const float4* x4 = (const float4*)sx3;
        float acc = 0.f;
        for (int t = 0; t < 64; ++t) {
            float4 wv = wr[t], xv = x4[t];
            acc += wv.x * xv.x + wv.y * xv.y + wv.z * xv.z + wv.w * xv.w;
        }
        shh[tid] = acc + CL1B[tid];
    }
    __syncthreads();
    if (tid < 18) {
        const float4* wr = (const float4*)(CL2W + (size_t)tid * 128);
        const float4* h4 = (const float4*)shh;
        float acc = 0.f;
        for (int t = 0; t < 32; ++t) {
            float4 wv = wr[t], xv = h4[t];
            acc += wv.x * xv.x + wv.y * xv.y + wv.z * xv.z + wv.w * xv.w;
        }
        out[b * 18 + tid] = acc + CL2B[tid];
    }
}

// ---------------------------------------------------------------------------

#define DI(i) ((const float*)d_in[i])

extern "C" void kernel_launch(void* const* d_in, const int* in_sizes, int n_in,
                              void* d_out, int out_size, void* d_ws, size_t ws_size,
                              hipStream_t stream) {
    float* ws    = (float*)d_ws;
    float* P     = ws;                  // 3*32*32*196   = 602112
    float* R     = P + 602112;          // 3*32*256*32   = 786432
    float* feats = R + 786432;          // 32*1536       = 49152
    float* xf    = feats + 49152;       // 32*256
    float* U1    = xf + 8192;
    float* XF1   = U1 + 8192;
    float* M2a   = XF1 + 8192;          // 64*256
    float* M2b   = M2a + 16384;

    // feats[:,768:1536] is accumulated atomically by k_cross -> zero it (ws is poisoned 0xAA)
    hipMemsetAsync(feats, 0, 49152 * sizeof(float), stream);

    k_patch_conv<<<1344, 256, 0, stream>>>(DI(0), DI(1), DI(2),
                                           DI(3), DI(7), DI(11),
                                           DI(4), DI(8), DI(12), P);
    k_proj<<<192, 128, 0, stream>>>(P, DI(5), DI(9), DI(13), DI(6), DI(10), DI(14), R, feats);
    k_cross<<<256, 256, 0, stream>>>(R, DI(15), DI(16), DI(17), DI(18), DI(19), DI(20), feats);
    k_fuse<<<32, 256, 0, stream>>>(feats, DI(21), DI(22), DI(23), DI(24), DI(25), DI(26),
                                   DI(27), DI(28), xf);
    k_m1<<<32, 256, 0, stream>>>(xf, U1, DI(29), DI(30), DI(31), DI(32), DI(33), DI(34),
                                 DI(36), DI(37), 0);
    k_m1<<<32, 256, 0, stream>>>(U1, XF1, DI(29), DI(30), DI(31), DI(32), DI(33), DI(34),
                                 DI(36), DI(37), 1);
    k_m2<<<64, 256, 0, stream>>>(XF1, M2a, 1, DI(38), DI(39), DI(40), DI(41), DI(42), DI(43),
                                 DI(44), DI(45), DI(46), 0);
    k_m2<<<64, 256, 0, stream>>>(M2a, M2b, 0, DI(38), DI(39), DI(40), DI(41), DI(42), DI(43),
                                 DI(44), DI(45), DI(46), 1);
    k_final<<<32, 256, 0, stream>>>(M2b, XF1, DI(47), DI(48), DI(49), DI(50), (float*)d_out);
}

// Round 6
// 1215.230 us; speedup vs baseline: 1.1845x; 1.1845x over previous
//
#include <hip/hip_runtime.h>
#include <math.h>

// ---------------------------------------------------------------------------
// MultiSensor TSCMamba forward, fp32 throughout.
//   k_tr / k_p4  : one-time weight repacks (coalesced-read layouts)
//   k_patch_conv : 16x16/s16 patch conv, 2-phase async global_load_lds pipeline
//   k_proj       : P @ proj_w.T + gelu -> R; feats[:,0:768] (means)
//   k_cross      : 3 pair cross-convs + BN + gelu, channel means -> feats[:,768:]
//   k_fuse       : feats @ fu_w.T + BN + gelu + LayerNorm -> xf
//   k_m1 (x2)    : mamba L=1 (closed form)
//   k_m2 (x2)    : mamba D=1, L=256 scan, 64 seqs
//   k_final      : combine + classifier
// ---------------------------------------------------------------------------

__device__ __forceinline__ float gelu_f(float x) {
    return 0.5f * x * (1.0f + erff(x * 0.70710678118654752f));
}
__device__ __forceinline__ float silu_f(float x) {
    return x / (1.0f + expf(-x));
}
__device__ __forceinline__ float softplus_f(float x) {
    return (x > 20.0f) ? x : log1pf(expf(x));
}

// async global->LDS, 16B per lane; lds dest = wave-uniform base + lane*16
__device__ __forceinline__ void gl2lds(const float4* g, float4* l) {
    __builtin_amdgcn_global_load_lds((const __attribute__((address_space(1))) void*)g,
                                     (__attribute__((address_space(3))) void*)l,
                                     16, 0, 0);
}

// ---------------------------------------------------------------------------
// Repack kernels.
// k_tr: dst[C][R] = src[R][C]^T  (R,C multiples of 32)
// ---------------------------------------------------------------------------
__global__ __launch_bounds__(256)
void k_tr(const float* __restrict__ src, float* __restrict__ dst, int R, int C) {
    __shared__ float t[32][33];
    int ctiles = C >> 5;
    int bx = blockIdx.x % ctiles, by = blockIdx.x / ctiles;
    int c0 = bx * 32, r0 = by * 32;
    int tx = threadIdx.x & 31, ty = threadIdx.x >> 5;
#pragma unroll
    for (int k = 0; k < 4; ++k) {
        int r = ty + k * 8;
        t[r][tx] = src[(size_t)(r0 + r) * C + c0 + tx];
    }
    __syncthreads();
#pragma unroll
    for (int k = 0; k < 4; ++k) {
        int r = ty + k * 8;
        dst[(size_t)(c0 + r) * R + r0 + tx] = t[tx][r];
    }
}

// k_p4: src[E][4*Dq] -> dst4[Dq][E], dst4[dq*E+e] = float4(src[e][4dq..4dq+3])
__global__ __launch_bounds__(256)
void k_p4(const float* __restrict__ src, float4* __restrict__ dst, int E, int Dq) {
    int idx = blockIdx.x * 256 + threadIdx.x;
    if (idx >= E * Dq) return;
    int e = idx / Dq, dq = idx % Dq;  // consecutive lanes: same e, consecutive dq -> coalesced read
    dst[(size_t)dq * E + e] = *(const float4*)(src + (size_t)e * 4 * Dq + 4 * dq);
}

// ---------------------------------------------------------------------------
// Kernel 1: patch conv.  grid = 3*32*14, 256 threads, 2 blocks/CU.
// Per ci: W(ci) -> ws4 (single buf), X(ci+1) -> xs4[^1] (double buf), all via
// global_load_lds. Raw barriers + counted vmcnt(4) keep the X prefetch in
// flight across the barrier (only the youngest 4 ops are the prefetch).
// ---------------------------------------------------------------------------
__global__ __launch_bounds__(256, 2)
void k_patch_conv(const float* __restrict__ X0, const float* __restrict__ X1, const float* __restrict__ X2,
                  const float* __restrict__ W0, const float* __restrict__ W1, const float* __restrict__ W2,
                  const float* __restrict__ B0, const float* __restrict__ B1, const float* __restrict__ B2,
                  float* __restrict__ P) {
    int bid = blockIdx.x;
    int s = bid / 448; int rem = bid % 448; int b = rem / 14; int ph = rem % 14;
    const float* X  = (s == 0) ? X0 : ((s == 1) ? X1 : X2);
    const float* W  = (s == 0) ? W0 : ((s == 1) ? W1 : W2);
    const float* Bb = (s == 0) ? B0 : ((s == 1) ? B1 : B2);

    __shared__ float4 xs4[2][1024];   // 16 rows x 56 f4 (+pad chunks 896..1023), linear for gload_lds
    __shared__ float4 ws4[2048];      // [co][kh*4+kwq]
    __shared__ float  red[16 * 112];  // cross-wave reduction

    int tid = threadIdx.x;
    int wave = tid >> 6, lane = tid & 63;
    int ij = tid & 3;
    int i  = ij & 1;        // pw half  (pw = i*7 + p)
    int j  = ij >> 1;       // co half  (co = j*16 + c)
    int k  = tid >> 2;      // 0..63 over (kh, kw-quad)
    int kh = k >> 2;
    int kwq = k & 3;

    const float4* xg = (const float4*)X + (size_t)(b * 32) * 12544 + ph * 896;
    const float4* wg = (const float4*)W;

    // prologue: stage X(0)
#pragma unroll
    for (int q = 0; q < 4; ++q) {
        int chunk = wave * 4 + q;
        int idx = chunk * 64 + lane; if (idx > 895) idx = 895;  // pad chunks re-read (L1-hot), never consumed
        gl2lds(xg + idx, &xs4[0][chunk * 64]);
    }

    float acc[7][16];
#pragma unroll
    for (int p = 0; p < 7; ++p)
#pragma unroll
        for (int c = 0; c < 16; ++c) acc[p][c] = 0.f;

    for (int ci = 0; ci < 32; ++ci) {
        asm volatile("s_barrier" ::: "memory");   // A: prev compute done -> ws4 / xs4[^1] free
        // W(ci): 32 chunks of 1KB; chunk = co; contiguous 64 f4 per chunk
#pragma unroll
        for (int q = 0; q < 8; ++q) {
            int c = wave * 8 + q;
            gl2lds(wg + (size_t)c * 2048 + ci * 64 + lane, &ws4[c * 64]);
        }
        if (ci < 31) {
            const float4* xgn = xg + (size_t)(ci + 1) * 12544;
#pragma unroll
            for (int q = 0; q < 4; ++q) {
                int chunk = wave * 4 + q;
                int idx = chunk * 64 + lane; if (idx > 895) idx = 895;
                gl2lds(xgn + idx, &xs4[(ci + 1) & 1][chunk * 64]);
            }
            asm volatile("s_waitcnt vmcnt(4)" ::: "memory");  // drain X(ci)+W(ci); keep X(ci+1)
        } else {
            asm volatile("s_waitcnt vmcnt(0)" ::: "memory");
        }
        asm volatile("s_barrier" ::: "memory");   // B: all waves' data landed

        const float4* xr_ = &xs4[ci & 1][kh * 56 + i * 28 + kwq];
        float4 xv[7];
#pragma unroll
        for (int p = 0; p < 7; ++p) xv[p] = xr_[p * 4];
#pragma unroll
        for (int c = 0; c < 16; ++c) {
            float4 wv = ws4[(j * 16 + c) * 64 + k];
#pragma unroll
            for (int p = 0; p < 7; ++p) {
                acc[p][c] += xv[p].x * wv.x + xv[p].y * wv.y + xv[p].z * wv.z + xv[p].w * wv.w;
            }
        }
    }

    // reduce over k within wave (16 k-values per wave on lane bits 2..5)
#pragma unroll
    for (int p = 0; p < 7; ++p) {
#pragma unroll
        for (int c = 0; c < 16; ++c) {
            float v = acc[p][c];
            v += __shfl_xor(v, 4);
            v += __shfl_xor(v, 8);
            v += __shfl_xor(v, 16);
            v += __shfl_xor(v, 32);
            acc[p][c] = v;
        }
    }
    if (lane < 4) {
#pragma unroll
        for (int p = 0; p < 7; ++p)
#pragma unroll
            for (int c = 0; c < 16; ++c)
                red[(wave * 4 + lane) * 112 + p * 16 + c] = acc[p][c];
    }
    __syncthreads();
    for (int t = tid; t < 448; t += 256) {
        int ij2 = t / 112, v = t % 112;
        int p = v / 16, c = v % 16;
        float sum = red[(0 * 4 + ij2) * 112 + v] + red[(1 * 4 + ij2) * 112 + v] +
                    red[(2 * 4 + ij2) * 112 + v] + red[(3 * 4 + ij2) * 112 + v];
        int pw = (ij2 & 1) * 7 + p;
        int co = (ij2 >> 1) * 16 + c;
        P[(((size_t)s * 32 + b) * 32 + co) * 196 + ph * 14 + pw] = sum + Bb[co];
    }
}

// ---------------------------------------------------------------------------
// Kernel 2: projection (196 -> 256) + gelu + swapaxes; fused means.
// PWP = packed proj_w: PWP[s][nq*256 + l] = float4(pw[l][4nq..])  -> coalesced.
// ---------------------------------------------------------------------------
__global__ __launch_bounds__(128)
void k_proj(const float* __restrict__ P, const float4* __restrict__ PWP,
            const float* __restrict__ PB0, const float* __restrict__ PB1, const float* __restrict__ PB2,
            float* __restrict__ R, float* __restrict__ feats) {
    int bid = blockIdx.x;
    int s = bid / 64; int r2 = bid % 64; int b = r2 >> 1; int half = r2 & 1;
    const float* PB = (s == 0) ? PB0 : ((s == 1) ? PB1 : PB2);
    const float4* pwp = PWP + (size_t)s * 12544;

    __shared__ __align__(16) float4 ps4[32 * 49];  // P[b]: 32 co x 196 n
    const float4* src = (const float4*)(P + ((size_t)s * 32 + b) * 6272);
    for (int t = threadIdx.x; t < 1568; t += 128) ps4[t] = src[t];
    __syncthreads();

    int l = half * 128 + threadIdx.x;
    float acc[32];
#pragma unroll
    for (int c = 0; c < 32; ++c) acc[c] = 0.f;

    for (int n4 = 0; n4 < 49; ++n4) {
        float4 pv = pwp[n4 * 256 + l];
#pragma unroll
        for (int c = 0; c < 32; ++c) {
            float4 xv = ps4[c * 49 + n4];
            acc[c] += pv.x * xv.x + pv.y * xv.y + pv.z * xv.z + pv.w * xv.w;
        }
    }
    float pbl = PB[l];
    float m = 0.f;
    float* Rrow = R + (((size_t)s * 32 + b) * 256 + l) * 32;
#pragma unroll
    for (int c = 0; c < 32; ++c) {
        float v = gelu_f(acc[c] + pbl);
        Rrow[c] = v;
        m += v;
    }
    feats[b * 1536 + s * 256 + l] = m * 0.03125f;
}

// ---------------------------------------------------------------------------
// Kernel 3: cross conv + BN + gelu, channel means only. CCWT[1536][256].
// ---------------------------------------------------------------------------
__global__ __launch_bounds__(256)
void k_cross(const float* __restrict__ R, const float* __restrict__ CCWT,
             const float* __restrict__ CCB, const float* __restrict__ CCG,
             const float* __restrict__ CCBETA, const float* __restrict__ CCRM,
             const float* __restrict__ CCRV, float* __restrict__ feats) {
    int b = blockIdx.x >> 3, cs = blockIdx.x & 7;
    int c0 = cs * 4;
    __shared__ __align__(16) float ls[3 * 256 * 8];  // [tensor][row][col c0-1..c0+4 zero-padded]
    for (int t = threadIdx.x; t < 4608; t += 256) {
        int ten = t / 1536; int r2 = t % 1536; int r = r2 / 6; int cc = r2 % 6;
        int cg = c0 - 1 + cc;
        float v = 0.f;
        if (cg >= 0 && cg < 32) v = R[(((size_t)ten * 32 + b) * 256 + r) * 32 + cg];
        ls[(ten * 256 + r) * 8 + cc] = v;
    }
    __syncthreads();

    int o = threadIdx.x;
    float a1[4] = {0, 0, 0, 0}, a2[4] = {0, 0, 0, 0}, a3[4] = {0, 0, 0, 0};

    for (int ii = 0; ii < 256; ++ii) {
        float w0 = CCWT[(ii * 3 + 0) * 256 + o];
        float w1 = CCWT[(ii * 3 + 1) * 256 + o];
        float w2 = CCWT[(ii * 3 + 2) * 256 + o];
        const float* U = &ls[(0 * 256 + ii) * 8];  // x
        const float* V = &ls[(1 * 256 + ii) * 8];  // y
        float4 ua = *(const float4*)U; float2 ub = *(const float2*)(U + 4);
        float4 va = *(const float4*)V; float2 vb = *(const float2*)(V + 4);
        float s0 = w0 * ua.x + w1 * ua.y + w2 * ua.z;
        float s1 = w0 * ua.y + w1 * ua.z + w2 * ua.w;
        float s2 = w0 * ua.z + w1 * ua.w + w2 * ub.x;
        float s3 = w0 * ua.w + w1 * ub.x + w2 * ub.y;
        float t0 = w0 * va.x + w1 * va.y + w2 * va.z;
        float t1 = w0 * va.y + w1 * va.z + w2 * va.w;
        float t2 = w0 * va.z + w1 * va.w + w2 * vb.x;
        float t3 = w0 * va.w + w1 * vb.x + w2 * vb.y;
        a1[0] += s0; a1[1] += s1; a1[2] += s2; a1[3] += s3;
        a2[0] += s0; a2[1] += s1; a2[2] += s2; a2[3] += s3;
        a3[0] += t0; a3[1] += t1; a3[2] += t2; a3[3] += t3;
    }
    for (int ii = 0; ii < 256; ++ii) {
        float w0 = CCWT[(768 + ii * 3 + 0) * 256 + o];
        float w1 = CCWT[(768 + ii * 3 + 1) * 256 + o];
        float w2 = CCWT[(768 + ii * 3 + 2) * 256 + o];
        const float* U = &ls[(1 * 256 + ii) * 8];  // y
        const float* V = &ls[(2 * 256 + ii) * 8];  // z
        float4 ua = *(const float4*)U; float2 ub = *(const float2*)(U + 4);
        float4 va = *(const float4*)V; float2 vb = *(const float2*)(V + 4);
        float s0 = w0 * ua.x + w1 * ua.y + w2 * ua.z;
        float s1 = w0 * ua.y + w1 * ua.z + w2 * ua.w;
        float s2 = w0 * ua.z + w1 * ua.w + w2 * ub.x;
        float s3 = w0 * ua.w + w1 * ub.x + w2 * ub.y;
        float t0 = w0 * va.x + w1 * va.y + w2 * va.z;
        float t1 = w0 * va.y + w1 * va.z + w2 * va.w;
        float t2 = w0 * va.z + w1 * va.w + w2 * vb.x;
        float t3 = w0 * va.w + w1 * vb.x + w2 * vb.y;
        a1[0] += s0; a1[1] += s1; a1[2] += s2; a1[3] += s3;
        a2[0] += t0; a2[1] += t1; a2[2] += t2; a2[3] += t3;
        a3[0] += t0; a3[1] += t1; a3[2] += t2; a3[3] += t3;
    }

    float inv = CCG[o] / sqrtf(CCRV[o] + 1e-5f);
    float sh = CCBETA[o] - CCRM[o] * inv;
    float bias = CCB[o];
    float s1 = 0.f, s2 = 0.f, s3 = 0.f;
#pragma unroll
    for (int c = 0; c < 4; ++c) {
        s1 += gelu_f((a1[c] + bias) * inv + sh);
        s2 += gelu_f((a2[c] + bias) * inv + sh);
        s3 += gelu_f((a3[c] + bias) * inv + sh);
    }
    float* fb = feats + b * 1536 + 768;
    atomicAdd(&fb[o],       s1 * 0.03125f);
    atomicAdd(&fb[256 + o], s2 * 0.03125f);
    atomicAdd(&fb[512 + o], s3 * 0.03125f);
}

// ---------------------------------------------------------------------------
// Kernel 4: fuse linear + BN + gelu + LayerNorm. FUWP packed-vec4.
// ---------------------------------------------------------------------------
__global__ __launch_bounds__(256)
void k_fuse(const float* __restrict__ feats, const float4* __restrict__ FUWP, const float* __restrict__ FUB,
            const float* __restrict__ FUG, const float* __restrict__ FUBETA, const float* __restrict__ FURM,
            const float* __restrict__ FURV, const float* __restrict__ LNG, const float* __restrict__ LNB,
            float* __restrict__ xf) {
    int b = blockIdx.x;
    __shared__ __align__(16) float4 sf4[384];
    const float4* src = (const float4*)(feats + (size_t)b * 1536);
    for (int t = threadIdx.x; t < 384; t += 256) sf4[t] = src[t];
    __syncthreads();

    int o = threadIdx.x;
    float acc = 0.f;
    for (int kq = 0; kq < 384; ++kq) {
        float4 wv = FUWP[kq * 256 + o];
        float4 xv = sf4[kq];
        acc += wv.x * xv.x + wv.y * xv.y + wv.z * xv.z + wv.w * xv.w;
    }
    float inv = FUG[o] / sqrtf(FURV[o] + 1e-5f);
    float f = (acc + FUB[o]) * inv + (FUBETA[o] - FURM[o] * inv);
    f = gelu_f(f);

    float s1 = f, s2 = f * f;
#pragma unroll
    for (int off = 32; off >= 1; off >>= 1) {
        s1 += __shfl_xor(s1, off);
        s2 += __shfl_xor(s2, off);
    }
    __shared__ float wred[8];
    int wave = threadIdx.x >> 6, lane = threadIdx.x & 63;
    if (lane == 0) { wred[wave * 2] = s1; wred[wave * 2 + 1] = s2; }
    __syncthreads();
    float mu  = (wred[0] + wred[2] + wred[4] + wred[6]) * (1.f / 256.f);
    float ex2 = (wred[1] + wred[3] + wred[5] + wred[7]) * (1.f / 256.f);
    float var = ex2 - mu * mu;
    xf[b * 256 + o] = (f - mu) / sqrtf(var + 1e-5f) * LNG[o] + LNB[o];
}

// ---------------------------------------------------------------------------
// Kernel 5: m1 mamba layer, L=1 closed form. Packed weights (coalesced).
// WinP[dq*2048 + layer*1024 + e], WdtP[rq*1024 + layer*512 + d],
// WoutP[dq*512 + layer*256 + o].
// ---------------------------------------------------------------------------
__global__ __launch_bounds__(256)
void k_m1(const float* __restrict__ Uin, float* __restrict__ Uout,
          const float4* __restrict__ WinP, const float* __restrict__ CW, const float* __restrict__ CB,
          const float* __restrict__ WX, const float4* __restrict__ WdtP, const float* __restrict__ BDT,
          const float* __restrict__ DP, const float4* __restrict__ WoutP, int layer) {
    const float* cw   = CW   + layer * 2048;
    const float* cb   = CB   + layer * 512;
    const float* Wx   = WX   + layer * 48 * 512;
    const float* bdt  = BDT  + layer * 512;
    const float* Dp   = DP   + layer * 512;

    int b = blockIdx.x, tid = threadIdx.x;
    __shared__ __align__(16) float su[256];
    __shared__ __align__(16) float sz[1024];
    __shared__ __align__(16) float sx[512];
    __shared__ __align__(16) float sdbc[48];
    __shared__ __align__(16) float sy[512];

    su[tid] = Uin[b * 256 + tid];
    __syncthreads();

    const float4* su4 = (const float4*)su;
    {
        float accq[4] = {0.f, 0.f, 0.f, 0.f};
        for (int dq = 0; dq < 64; ++dq) {
            float4 s4 = su4[dq];
#pragma unroll
            for (int q = 0; q < 4; ++q) {
                float4 w4 = WinP[dq * 2048 + layer * 1024 + q * 256 + tid];
                accq[q] += w4.x * s4.x + w4.y * s4.y + w4.z * s4.z + w4.w * s4.w;
            }
        }
#pragma unroll
        for (int q = 0; q < 4; ++q) sz[tid + q * 256] = accq[q];
    }
    __syncthreads();
#pragma unroll
    for (int q = 0; q < 2; ++q) {
        int d = tid + q * 256;
        sx[d] = silu_f(cb[d] + sz[d] * cw[d * 4 + 3]);  // K=4, L=1 -> only tap k=3
    }
    __syncthreads();
    if (tid < 48) {
        const float4* wr = (const float4*)(Wx + (size_t)tid * 512);
        const float4* sx4 = (const float4*)sx;
        float acc = 0.f;
        for (int t = 0; t < 128; ++t) {
            float4 wv = wr[t], xv = sx4[t];
            acc += wv.x * xv.x + wv.y * xv.y + wv.z * xv.z + wv.w * xv.w;
        }
        sdbc[tid] = acc;
    }
    __syncthreads();
    float bc = 0.f;
#pragma unroll
    for (int n = 0; n < 16; ++n) bc += sdbc[16 + n] * sdbc[32 + n];
    const float4* sdbc4 = (const float4*)sdbc;
#pragma unroll
    for (int q = 0; q < 2; ++q) {
        int d = tid + q * 256;
        float dtin = 0.f;
#pragma unroll
        for (int rq = 0; rq < 4; ++rq) {
            float4 w4 = WdtP[rq * 1024 + layer * 512 + d];
            float4 s4 = sdbc4[rq];
            dtin += w4.x * s4.x + w4.y * s4.y + w4.z * s4.z + w4.w * s4.w;
        }
        float dtv = softplus_f(dtin + bdt[d]);
        float xcv = sx[d];
        float y = dtv * xcv * bc + Dp[d] * xcv;
        y *= silu_f(sz[512 + d]);
        sy[d] = y;
    }
    __syncthreads();
    {
        const float4* sy4 = (const float4*)sy;
        float acc = 0.f;
        for (int dq = 0; dq < 128; ++dq) {
            float4 w4 = WoutP[dq * 512 + layer * 256 + tid];
            float4 s4 = sy4[dq];
            acc += w4.x * s4.x + w4.y * s4.y + w4.z * s4.z + w4.w * s4.w;
        }
        Uout[b * 256 + tid] = acc + su[tid];  // residual
    }
}

// ---------------------------------------------------------------------------
// Kernel 6: m2 mamba layer, D=1, L=256; 64 sequences (32 b x {fwd,flip}).
// ---------------------------------------------------------------------------
__global__ __launch_bounds__(256)
void k_m2(const float* __restrict__ SRC, float* __restrict__ DST, int first,
          const float* __restrict__ WIN, const float* __restrict__ CW, const float* __restrict__ CB,
          const float* __restrict__ WX, const float* __restrict__ WDT, const float* __restrict__ BDT,
          const float* __restrict__ ALOG, const float* __restrict__ DP, const float* __restrict__ WOUT,
          int layer) {
    const float* Win  = WIN  + layer * 4;
    const float* cw   = CW   + layer * 8;
    const float* cb   = CB   + layer * 2;
    const float* Wx   = WX   + layer * 66;
    const float* Wdt  = WDT  + layer * 2;
    const float* bdt  = BDT  + layer * 2;
    const float* Alog = ALOG + layer * 32;
    const float* Dp   = DP   + layer * 2;
    const float* Wout = WOUT + layer * 2;

    int v = blockIdx.x, b = v >> 1, dir = v & 1, l = threadIdx.x;
    __shared__ float sxc[256 * 2];
    __shared__ float sC[256 * 16];
    __shared__ float suu[256 * 32];
    __shared__ float sdt[256 * 2];
    __shared__ float sy[256 * 2];

    float u;
    if (first) u = 2.f * SRC[b * 256 + (dir ? (255 - l) : l)];
    else       u = SRC[v * 256 + l];

    float xc0 = u * Win[0], xc1 = u * Win[1];
    float z0  = u * Win[2], z1  = u * Win[3];
    sxc[l * 2 + 0] = xc0; sxc[l * 2 + 1] = xc1;
    __syncthreads();

    float xs0, xs1;
    {
        float a0 = cb[0], a1 = cb[1];
#pragma unroll
        for (int kk = 0; kk < 4; ++kk) {
            int lk = l - 3 + kk;
            if (lk >= 0) {
                a0 += sxc[lk * 2 + 0] * cw[kk];
                a1 += sxc[lk * 2 + 1] * cw[4 + kk];
            }
        }
        xs0 = silu_f(a0); xs1 = silu_f(a1);
    }
    float dbc0 = xs0 * Wx[0] + xs1 * Wx[1];
    float dt0 = softplus_f(dbc0 * Wdt[0] + bdt[0]);
    float dt1 = softplus_f(dbc0 * Wdt[1] + bdt[1]);
    sdt[l * 2 + 0] = dt0; sdt[l * 2 + 1] = dt1;
#pragma unroll
    for (int n = 0; n < 16; ++n) {
        float Bn = xs0 * Wx[(1 + n) * 2] + xs1 * Wx[(1 + n) * 2 + 1];
        float Cn = xs0 * Wx[(17 + n) * 2] + xs1 * Wx[(17 + n) * 2 + 1];
        sC[l * 16 + n] = Cn;
        suu[l * 32 + n]      = dt0 * Bn * xs0;
        suu[l * 32 + 16 + n] = dt1 * Bn * xs1;
    }
    __syncthreads();

    if (l < 32) {
        int d = l >> 4, n = l & 15;
        float A = -expf(Alog[d * 16 + n]);
        float h = 0.f;
#pragma unroll 4
        for (int t = 0; t < 256; ++t) {
            float a = expf(sdt[t * 2 + d] * A);
            h = a * h + suu[t * 32 + l];
            float part = h * sC[t * 16 + n];
            part += __shfl_xor(part, 1);
            part += __shfl_xor(part, 2);
            part += __shfl_xor(part, 4);
            part += __shfl_xor(part, 8);
            if (n == 0) sy[t * 2 + d] = part;
        }
    }
    __syncthreads();
    {
        float y0 = sy[l * 2 + 0] + Dp[0] * xs0;
        float y1 = sy[l * 2 + 1] + Dp[1] * xs1;
        y0 *= silu_f(z0); y1 *= silu_f(z1);
        DST[v * 256 + l] = y0 * Wout[0] + y1 * Wout[1] + u;
    }
}

// ---------------------------------------------------------------------------
// Kernel 7: final combine + classifier.
// ---------------------------------------------------------------------------
__global__ __launch_bounds__(256)
void k_final(const float* __restrict__ M2b, const float* __restrict__ XF1,
             const float* __restrict__ CL1W, const float* __restrict__ CL1B,
             const float* __restrict__ CL2W, const float* __restrict__ CL2B,
             float* __restrict__ out) {
    int b = blockIdx.x, tid = threadIdx.x;
    __shared__ __align__(16) float sx3[256];
    __shared__ __align__(16) float shh[128];
    sx3[tid] = M2b[(2 * b) * 256 + tid] + M2b[(2 * b + 1) * 256 + tid] + 2.f * XF1[b * 256 + tid];
    __syncthreads();
    if (tid < 128) {
        const float4* wr = (const float4*)(CL1W + (size_t)tid * 256);
        const float4* x4 = (const float4*)sx3;
        float acc = 0.f;
        for (int t = 0; t < 64; ++t) {
            float4 wv = wr[t], xv = x4[t];
            acc += wv.x * xv.x + wv.y * xv.y + wv.z * xv.z + wv.w * xv.w;
        }
        shh[tid] = acc + CL1B[tid];
    }
    __syncthreads();
    if (tid < 18) {
        const float4* wr = (const float4*)(CL2W + (size_t)tid * 128);
        const float4* h4 = (const float4*)shh;
        float acc = 0.f;
        for (int t = 0; t < 32; ++t) {
            float4 wv = wr[t], xv = h4[t];
            acc += wv.x * xv.x + wv.y * xv.y + wv.z * xv.z + wv.w * xv.w;
        }
        out[b * 18 + tid] = acc + CL2B[tid];
    }
}

// ---------------------------------------------------------------------------

#define DI(i) ((const float*)d_in[i])

extern "C" void kernel_launch(void* const* d_in, const int* in_sizes, int n_in,
                              void* d_out, int out_size, void* d_ws, size_t ws_size,
                              hipStream_t stream) {
    float* ws    = (float*)d_ws;
    float* P     = ws;                   // 602112
    float* R     = P + 602112;           // 786432
    float* feats = R + 786432;           // 49152
    float* xf    = feats + 49152;        // 8192
    float* U1    = xf + 8192;            // 8192
    float* XF1   = U1 + 8192;            // 8192
    float* M2a   = XF1 + 8192;           // 16384
    float* M2b   = M2a + 16384;          // 16384
    float* CCWT  = M2b + 16384;          // 393216
    float* FUWP  = CCWT + 393216;        // 393216
    float* WinP  = FUWP + 393216;        // 524288
    float* WdtP  = WinP + 524288;        // 16384
    float* WoutP = WdtP + 16384;         // 262144
    float* PWP   = WoutP + 262144;       // 150528  (3 x 49*256*4)

    hipMemsetAsync(feats, 0, 49152 * sizeof(float), stream);

    // weight repacks (tiny; one-time per call)
    k_tr<<<384, 256, 0, stream>>>(DI(15), CCWT, 256, 1536);
    k_p4<<<49,  256, 0, stream>>>(DI(5),  (float4*)(PWP),          256, 49);
    k_p4<<<49,  256, 0, stream>>>(DI(9),  (float4*)(PWP + 50176),  256, 49);
    k_p4<<<49,  256, 0, stream>>>(DI(13), (float4*)(PWP + 100352), 256, 49);
    k_p4<<<384, 256, 0, stream>>>(DI(21), (float4*)FUWP,  256,  384);
    k_p4<<<512, 256, 0, stream>>>(DI(29), (float4*)WinP,  2048, 64);
    k_p4<<<16,  256, 0, stream>>>(DI(33), (float4*)WdtP,  1024, 4);
    k_p4<<<256, 256, 0, stream>>>(DI(37), (float4*)WoutP, 512,  128);

    k_patch_conv<<<1344, 256, 0, stream>>>(DI(0), DI(1), DI(2),
                                           DI(3), DI(7), DI(11),
                                           DI(4), DI(8), DI(12), P);
    k_proj<<<192, 128, 0, stream>>>(P, (const float4*)PWP, DI(6), DI(10), DI(14), R, feats);
    k_cross<<<256, 256, 0, stream>>>(R, CCWT, DI(16), DI(17), DI(18), DI(19), DI(20), feats);
    k_fuse<<<32, 256, 0, stream>>>(feats, (const float4*)FUWP, DI(22), DI(23), DI(24), DI(25),
                                   DI(26), DI(27), DI(28), xf);
    k_m1<<<32, 256, 0, stream>>>(xf, U1, (const float4*)WinP, DI(30), DI(31), DI(32),
                                 (const float4*)WdtP, DI(34), DI(36), (const float4*)WoutP, 0);
    k_m1<<<32, 256, 0, stream>>>(U1, XF1, (const float4*)WinP, DI(30), DI(31), DI(32),
                                 (const float4*)WdtP, DI(34), DI(36), (const float4*)WoutP, 1);
    k_m2<<<64, 256, 0, stream>>>(XF1, M2a, 1, DI(38), DI(39), DI(40), DI(41), DI(42), DI(43),
                                 DI(44), DI(45), DI(46), 0);
    k_m2<<<64, 256, 0, stream>>>(M2a, M2b, 0, DI(38), DI(39), DI(40), DI(41), DI(42), DI(43),
                                 DI(44), DI(45), DI(46), 1);
    k_final<<<32, 256, 0, stream>>>(M2b, XF1, DI(47), DI(48), DI(49), DI(50), (float*)d_out);
}